// Round 8
// baseline (4664.616 us; speedup 1.0000x reference)
//
#include <hip/hip_runtime.h>
#include <hip/hip_bf16.h>

#define BS 8
#define HID 64
#define NV 1024
#define NSTEP 64
#define HSTRIDE (BS*HID*NV)   // elems per h ping-pong buffer (bf16)

// out layout (float32, concatenated flat, element offsets):
//   imps  [8][1][1024][64]  at 0
//   preds [8][1][1024][64]  at 524288
//   reprs [8][64][1024][64] at 1048576
#define IMPS_OFF  0
#define PREDS_OFF 524288
#define REPRS_OFF 1048576

typedef unsigned short u16;
typedef __attribute__((ext_vector_type(8))) short bf8;   // 8 bf16 = one MFMA operand
typedef __attribute__((ext_vector_type(4))) float f4;    // 4 f32 accumulator

// inter-block barrier counters: device global (NEVER in ws — R7 aliased ws and hung)
__device__ int g_bar[128];   // one 64B-padded slot per batch (8 used)

__device__ __forceinline__ u16 f2bf(float f){
    __hip_bfloat16 h = __float2bfloat16(f);
    return *reinterpret_cast<u16*>(&h);
}
// read 8 f32 from global, pack to bf8
__device__ __forceinline__ bf8 ld8bf(const float* src){
    float v[8];
    *(float4*)&v[0] = *(const float4*)src;
    *(float4*)&v[4] = *(const float4*)(src + 4);
    union { u16 u[8]; bf8 b; } r;
    #pragma unroll
    for (int j = 0; j < 8; ++j) r.u[j] = f2bf(v[j]);
    return r.b;
}

// ---------------- h0 -> bf16 h fragments: hff[b][hh][k][sel][lane][8] ----------------
// semantic: h row = hh*32 + sel*16 + (lane&15), v = k*32 + (lane>>4)*8 + j
__global__ void conv_k(const float* __restrict__ h0, u16* __restrict__ hws){
    int f = blockIdx.x * blockDim.x + threadIdx.x;     // 65536 frags
    int l   = f & 63;
    int sel = (f >> 6) & 1;
    int k   = (f >> 7) & 31;
    int hh  = (f >> 12) & 1;
    int row = hh*32 + sel*16 + (l & 15);
    int col = k*32 + (l >> 4)*8;
    bf8 p = ld8bf(h0 + (size_t)row*NV + col);
    *(bf8*)(hws + (size_t)f*8) = p;
}

// ---------------- graph -> bf16 B-fragments: gff[tile][wt][k][lane][8] ----------------
__global__ void frag_k(const float* __restrict__ g, u16* __restrict__ gff){
    int f = blockIdx.x * blockDim.x + threadIdx.x;     // 131072 frags
    int l    = f & 63;
    int k    = (f >> 6) & 31;
    int wt   = (f >> 11) & 1;
    int tile = f >> 12;
    int row = tile*32 + wt*16 + (l & 15);
    int col = k*32 + (l >> 4)*8;
    bf8 p = ld8bf(g + (size_t)row*NV + col);
    *(bf8*)(gff + (size_t)f*8) = p;
}

// ---------------- pre-transpose x/mask: xmt[b][t][v] = mask ? x : +INF ----------------
__global__ void prep_k(const float* __restrict__ x, const int* __restrict__ mask,
                       float* __restrict__ xmt){
    __shared__ float tx[64][65];
    __shared__ int   tm[64][65];
    int b  = blockIdx.x >> 4;
    int v0 = (blockIdx.x & 15) << 6;
    int tid = threadIdx.x;
    int q = tid >> 6, l = tid & 63;
    #pragma unroll 4
    for (int r = 0; r < 16; ++r){
        int vv = r*4 + q;
        size_t idx = ((size_t)b*NV + v0 + vv)*64 + l;   // x[b][0][v][t], coalesced in t
        tx[vv][l] = x[idx];
        tm[vv][l] = mask[idx];
    }
    __syncthreads();
    #pragma unroll 4
    for (int r = 0; r < 16; ++r){
        int tt = r*4 + q;
        float xv = tx[l][tt];
        xmt[((size_t)b*NSTEP + tt)*NV + v0 + l] = tm[l][tt] ? xv : __builtin_inff();
    }
}

// ---------------- preds[t=0] = W_init . h0 + b_init ; zero barrier counters ----------------
__global__ void init_k(const float* __restrict__ h0, const float* __restrict__ Wini,
                       const float* __restrict__ bini, float* __restrict__ out,
                       float* __restrict__ predsT){
    if (blockIdx.x == 0 && threadIdx.x < 128) g_bar[threadIdx.x] = 0;
    int v = blockIdx.x * blockDim.x + threadIdx.x;
    if (v < NV){
        float s = 0.f;
        for (int h = 0; h < HID; ++h) s += h0[h*NV + v] * Wini[h];
        s += bini[0];
        for (int b = 0; b < BS; ++b){
            out[PREDS_OFF + (size_t)b*65536 + (size_t)v*64] = s;
            predsT[(size_t)b*NSTEP*NV + v] = s;
        }
    }
}

// ---------------- persistent recurrence: all 64 steps in one plain launch ----------------
// grid: 256 blocks = 8 batches x 32 node-tiles = 1 block/CU (all co-resident).
// 256 threads = 4 waves (2 wt x 2 hh). static LDS ~19.3 KB (< 64 KB limit).
// Per-batch (32-block) barrier on monotone device-global counters (reset by init_k).
__global__ __launch_bounds__(256, 1) void persist_k(
    u16* __restrict__ hws,
    const u16* __restrict__ gff, const float* __restrict__ ig,
    const float* __restrict__ Whh,
    const float* __restrict__ xmt, float* __restrict__ predsT,
    const float* __restrict__ Wih, const float* __restrict__ bih,
    const float* __restrict__ bhh,
    const float* __restrict__ Wini, const float* __restrict__ bini,
    const float* __restrict__ Wo, const float* __restrict__ bo,
    float* out, float* __restrict__ rtmp, int staged)
{
    __shared__ float xh_s[NV];                  // 4 KB
    __shared__ __align__(16) u16 hdb[32][72];   // 4.6 KB  h_diff bf16 [w][h]
    __shared__ __align__(16) float hnf[32][68]; // 8.5 KB  h_new  f32 [w][h]
    __shared__ float xg_s[32];
    __shared__ float r1[8][33], r2[8][33];

    const int tid  = threadIdx.x;
    const int b    = blockIdx.x >> 5;           // batch
    const int tile = blockIdx.x & 31;           // node tile (tile%8 = XCD)
    const int w0   = tile << 5;
    const int lane = tid & 63;
    const int wv   = tid >> 6;
    const int wt   = wv & 1;                    // w 16-tile
    const int hh   = wv >> 1;                   // h 32-half
    const int m16  = lane & 15;
    const int q    = lane >> 4;

    // ---- W_hh fragments: t-invariant, loaded ONCE for all 64 steps ----
    bf8 wf[3][2][2];
    #pragma unroll
    for (int gi = 0; gi < 3; ++gi)
        #pragma unroll
        for (int ht = 0; ht < 2; ++ht)
            #pragma unroll
            for (int ks = 0; ks < 2; ++ks)
                wf[gi][ht][ks] = ld8bf(Whh
                    + (size_t)(gi*64 + hh*32 + ht*16 + m16)*64 + ks*32 + q*8);

    const u16* gB = gff + ((size_t)(tile*2 + wt)*32)*512 + lane*8;
    const int v4 = tid * 4;
    int* const cb = g_bar + (b << 4);           // this batch's 64B-padded counter

    #pragma unroll 1
    for (int t = 0; t < NSTEP; ++t){
        const u16* hin  = hws + (size_t)(t & 1) * HSTRIDE;
        u16*       hout = hws + (size_t)((t+1) & 1) * HSTRIDE;

        // ---- phase 0a: coalesced x/preds loads (consumed after MFMA stream) ----
        float4 xm = *(const float4*)(xmt    + ((size_t)b*NSTEP + t)*NV + v4);
        float4 pv = *(const float4*)(predsT + ((size_t)b*NSTEP + t)*NV + v4);

        // ---- phase 2: h_diff = h . graph^T, frag-coalesced 1KB wave loads ----
        const u16* hA = hin + (size_t)b*65536 + (size_t)hh*32768 + lane*8;
        f4 accA0 = {0.f,0.f,0.f,0.f}, accA1 = {0.f,0.f,0.f,0.f};
        #pragma unroll
        for (int k = 0; k < 32; ++k){
            bf8 a0 = *(const bf8*)(hA + k*1024);          // h rows hh*32 + 0..15
            bf8 a1 = *(const bf8*)(hA + k*1024 + 512);    // h rows hh*32 + 16..31
            bf8 gb = *(const bf8*)(gB + k*512);
            accA0 = __builtin_amdgcn_mfma_f32_16x16x32_bf16(a0, gb, accA0, 0, 0, 0);
            accA1 = __builtin_amdgcn_mfma_f32_16x16x32_bf16(a1, gb, accA1, 0, 0, 0);
        }
        // acc: col = m16 -> w = wt*16+m16 ; row = q*4+r -> h = hh*32 + sel*16 + q*4+r

        // ---- phase 0b: x_hat select + h_diff publish ----
        {
            float4 xh;
            xh.x = (__float_as_uint(xm.x) == 0x7f800000u) ? pv.x : xm.x;
            xh.y = (__float_as_uint(xm.y) == 0x7f800000u) ? pv.y : xm.y;
            xh.z = (__float_as_uint(xm.z) == 0x7f800000u) ? pv.z : xm.z;
            xh.w = (__float_as_uint(xm.w) == 0x7f800000u) ? pv.w : xm.w;
            *(float4*)&xh_s[v4] = xh;
        }
        #pragma unroll
        for (int ht = 0; ht < 2; ++ht){
            f4 a = ht ? accA1 : accA0;
            ushort4 pk;
            pk.x = f2bf(a[0]); pk.y = f2bf(a[1]); pk.z = f2bf(a[2]); pk.w = f2bf(a[3]);
            *(ushort4*)&hdb[wt*16 + m16][hh*32 + ht*16 + q*4] = pk;
        }
        __syncthreads();   // B1: xh_s + hdb ready

        // ---- phase 1: x_g[w] = sum_v ig[w][v]*x_hat[v] (f32 direct, shfl reduce) ----
        {
            int w = tid >> 3, p = tid & 7;
            const float* igr = ig + (size_t)(w0 + w)*NV + p*8;
            float acc = 0.f;
            #pragma unroll
            for (int k = 0; k < 16; ++k){
                float4 ga = *(const float4*)(igr + k*64);
                float4 gc = *(const float4*)(igr + k*64 + 4);
                const float* xv = &xh_s[p*8 + k*64];
                acc += ga.x*xv[0] + ga.y*xv[1] + ga.z*xv[2] + ga.w*xv[3]
                     + gc.x*xv[4] + gc.y*xv[5] + gc.z*xv[6] + gc.w*xv[7];
            }
            acc += __shfl_xor(acc, 1);
            acc += __shfl_xor(acc, 2);
            acc += __shfl_xor(acc, 4);
            if (p == 0) xg_s[w] = acc;
        }

        // ---- phase 3: gh = W_hh . h_diff (K=64): A = wf regs, B = hdb ----
        f4 accG[3][2];
        #pragma unroll
        for (int i = 0; i < 3; ++i){ accG[i][0] = (f4){0,0,0,0}; accG[i][1] = (f4){0,0,0,0}; }
        #pragma unroll
        for (int ks = 0; ks < 2; ++ks){
            bf8 bfr = *(const bf8*)&hdb[wt*16 + m16][ks*32 + q*8];
            #pragma unroll
            for (int gi = 0; gi < 3; ++gi){
                #pragma unroll
                for (int ht = 0; ht < 2; ++ht){
                    accG[gi][ht] = __builtin_amdgcn_mfma_f32_16x16x32_bf16(
                        wf[gi][ht][ks], bfr, accG[gi][ht], 0, 0, 0);
                }
            }
        }
        __syncthreads();   // B2: xg_s ready

        // ---- phase 4: GRU elementwise (h_diff straight from accA regs) ----
        {
            int wme = wt*16 + m16;
            float xg = xg_s[wme];
            #pragma unroll
            for (int ht = 0; ht < 2; ++ht){
                f4 hd4 = ht ? accA1 : accA0;
                f4 hn4;
                int hb4 = hh*32 + ht*16 + q*4;
                #pragma unroll
                for (int r = 0; r < 4; ++r){
                    int h = hb4 + r;
                    float ir  = xg * Wih[h]       + bih[h];
                    float iz  = xg * Wih[64 + h]  + bih[64 + h];
                    float inn = xg * Wih[128 + h] + bih[128 + h];
                    float hr  = accG[0][ht][r] + bhh[h];
                    float hz  = accG[1][ht][r] + bhh[64 + h];
                    float hnn = accG[2][ht][r] + bhh[128 + h];
                    float rg = 1.f / (1.f + __expf(-(ir + hr)));
                    float zg = 1.f / (1.f + __expf(-(iz + hz)));
                    float ng = tanhf(inn + rg * hnn);
                    hn4[r] = (1.f - zg) * ng + zg * hd4[r];
                }
                *(f4*)&hnf[wme][hb4] = hn4;
            }
        }
        __syncthreads();   // B3: hnf ready

        // ---- phase 5: outputs ----
        {   // head partial dots over h (8 groups of 8)
            int w2 = tid & 31, hg = tid >> 5;
            float s1 = 0.f, s2 = 0.f;
            #pragma unroll
            for (int j = 0; j < 8; ++j){
                float hv = hnf[w2][hg*8 + j];
                s1 += Wini[hg*8 + j] * hv;
                s2 += Wo[hg*8 + j]   * hv;
            }
            r1[hg][w2] = s1; r2[hg][w2] = s2;
        }
        {   // h_out in hff fragment order (1KB contiguous per wave) + reprs staging
            int h = tid >> 2, wq = tid & 3;
            float vals[8];
            #pragma unroll
            for (int j = 0; j < 8; ++j) vals[j] = hnf[wq*8 + j][h];
            u16 pk[8];
            #pragma unroll
            for (int j = 0; j < 8; ++j) pk[j] = f2bf(vals[j]);
            size_t ho = (size_t)b*65536
                      + ((size_t)((h >> 5)*32 + tile)*2 + ((h >> 4) & 1))*512
                      + wq*128 + (h & 15)*8;
            *(uint4*)(hout + ho) = *(uint4*)pk;
            if (staged){
                float* rp = rtmp + (((size_t)t*BS + b)*HID + h)*NV + w0 + wq*8;
                float4 a = {vals[0], vals[1], vals[2], vals[3]};
                float4 c = {vals[4], vals[5], vals[6], vals[7]};
                *(float4*)rp       = a;
                *(float4*)(rp + 4) = c;
            } else {
                size_t rb = REPRS_OFF + (((size_t)b*HID + h)*NV + w0 + wq*8)*64 + t;
                #pragma unroll
                for (int j = 0; j < 8; ++j) out[rb + (size_t)j*64] = vals[j];
            }
        }
        __syncthreads();   // B4: r1/r2 ready
        if (tid < 32){
            int w = tid, wg = w0 + w;
            float s1 = 0.f, s2 = 0.f;
            #pragma unroll
            for (int hg = 0; hg < 8; ++hg){ s1 += r1[hg][w]; s2 += r2[hg][w]; }
            s1 += bini[0]; s2 += bo[0];
            size_t base = (size_t)b*65536 + (size_t)wg*64;
            out[IMPS_OFF + base + t] = s2;                 // imps[t]
            if (t < NSTEP - 1){
                out[PREDS_OFF + base + t + 1] = s1;        // preds[t+1]
                predsT[((size_t)b*NSTEP + t + 1)*NV + wg] = s1;
            }
        }

        // ---- per-batch inter-block barrier (32 blocks of batch b, monotone counter) ----
        if (t < NSTEP - 1){
            __threadfence();                 // release: flush this block's writes
            __syncthreads();                 // B5: whole block fenced
            if (tid == 0){
                __hip_atomic_fetch_add(cb, 1, __ATOMIC_RELEASE, __HIP_MEMORY_SCOPE_AGENT);
                int target = 32 * (t + 1);
                while (__hip_atomic_load(cb, __ATOMIC_ACQUIRE, __HIP_MEMORY_SCOPE_AGENT) < target)
                    __builtin_amdgcn_s_sleep(2);
            }
            __syncthreads();                 // B6: all threads see counter reached
            __threadfence();                 // acquire: invalidate stale L1 lines
        }
    }
}

// ---------------- reprs staging [t][b][h][v] -> out [b][h][v][t] ----------------
__global__ void transpose_k(const float* __restrict__ rtmp, float* __restrict__ out){
    __shared__ float tile[64][65];
    int bh = blockIdx.x >> 4;          // 0..511 = b*64 + h
    int b  = bh >> 6, h = bh & 63;
    int v0 = (blockIdx.x & 15) << 6;
    int tid = threadIdx.x;
    int q = tid >> 6, l = tid & 63;
    #pragma unroll 4
    for (int r = 0; r < 16; ++r){
        int tt = r*4 + q;
        tile[tt][l] = rtmp[(((size_t)tt*BS + b)*HID + h)*NV + v0 + l];
    }
    __syncthreads();
    #pragma unroll 4
    for (int r = 0; r < 16; ++r){
        int vv = r*4 + q;
        out[REPRS_OFF + (((size_t)b*HID + h)*NV + v0 + vv)*64 + l] = tile[l][vv];
    }
}

extern "C" void kernel_launch(void* const* d_in, const int* in_sizes, int n_in,
                              void* d_out, int out_size, void* d_ws, size_t ws_size,
                              hipStream_t stream) {
    const float* x     = (const float*)d_in[0];
    const int*   mask  = (const int*)  d_in[1];
    const float* graph = (const float*)d_in[2];
    const float* ind   = (const float*)d_in[3];
    const float* h0    = (const float*)d_in[4];
    const float* Wini  = (const float*)d_in[5];
    const float* bini  = (const float*)d_in[6];
    const float* Wo    = (const float*)d_in[7];
    const float* bo    = (const float*)d_in[8];
    const float* Wih   = (const float*)d_in[9];
    const float* Whh   = (const float*)d_in[10];
    const float* bih   = (const float*)d_in[11];
    const float* bhh   = (const float*)d_in[12];
    float* out = (float*)d_out;

    char* ws = (char*)d_ws;
    u16*   hws    = (u16*)(ws);                         // 2 x 1 MB bf16 h frags ping-pong
    u16*   gff    = (u16*)(ws + ((size_t)2<<20));       // 2 MB graph B-frags
    float* xmt    = (float*)(ws + ((size_t)4<<20));     // 2 MB x/mask merged transposed
    float* predsT = (float*)(ws + ((size_t)6<<20));     // 2 MB preds in [b][t][v]
    float* rtmp   = (float*)(ws + ((size_t)8<<20));     // 128 MB reprs staging
    size_t need_staged = ((size_t)8<<20) + (size_t)NSTEP*BS*HID*NV*4;
    int staged = (ws_size >= need_staged) ? 1 : 0;

    conv_k<<<dim3(256), dim3(256), 0, stream>>>(h0, hws);
    frag_k<<<dim3(512), dim3(256), 0, stream>>>(graph, gff);
    prep_k<<<dim3(128), dim3(256), 0, stream>>>(x, mask, xmt);
    init_k<<<dim3(4), dim3(256), 0, stream>>>(h0, Wini, bini, out, predsT);

    persist_k<<<dim3(256), dim3(256), 0, stream>>>(
        hws, gff, ind, Whh, xmt, predsT,
        Wih, bih, bhh, Wini, bini, Wo, bo, out, rtmp, staged);

    if (staged) transpose_k<<<dim3(8192), dim3(256), 0, stream>>>(rtmp, out);
}

// Round 10
// 905.565 us; speedup vs baseline: 5.1511x; 5.1511x over previous
//
#include <hip/hip_runtime.h>
#include <hip/hip_bf16.h>

#define BS 8
#define HID 64
#define NV 1024
#define NSTEP 64
#define HSTRIDE (BS*HID*NV)   // elems per h ping-pong buffer (bf16)

// out layout (float32, concatenated flat, element offsets):
//   imps  [8][1][1024][64]  at 0
//   preds [8][1][1024][64]  at 524288
//   reprs [8][64][1024][64] at 1048576
#define IMPS_OFF  0
#define PREDS_OFF 524288
#define REPRS_OFF 1048576

typedef unsigned short u16;
typedef __attribute__((ext_vector_type(8))) short bf8;          // 8 bf16 = one MFMA operand
typedef __attribute__((ext_vector_type(4))) float f4;           // 4 f32 (ext-vector, asm-safe)
typedef __attribute__((ext_vector_type(4))) unsigned int u32x4; // 16B (ext-vector, asm-safe)

// inter-block barrier counters: device global (NEVER in ws — R7 aliasing lesson)
__device__ int g_bar[128];   // one 64B-padded slot per batch (8 used)

__device__ __forceinline__ u16 f2bf(float f){
    __hip_bfloat16 h = __float2bfloat16(f);
    return *reinterpret_cast<u16*>(&h);
}
// read 8 f32 from global, pack to bf8
__device__ __forceinline__ bf8 ld8bf(const float* src){
    float v[8];
    *(float4*)&v[0] = *(const float4*)src;
    *(float4*)&v[4] = *(const float4*)(src + 4);
    union { u16 u[8]; bf8 b; } r;
    #pragma unroll
    for (int j = 0; j < 8; ++j) r.u[j] = f2bf(v[j]);
    return r.b;
}

// ---- cache-bypassing (coherent, LLC-level) accessors: sc0 sc1 ----
// NOTE: asm operands MUST be ext_vector types (HIP float4/uint4 are structs -> compile error)
__device__ __forceinline__ bf8 ldcc(const u16* p){
    bf8 r;
    asm volatile("global_load_dwordx4 %0, %1, off sc0 sc1" : "=v"(r) : "v"(p));
    return r;
}
__device__ __forceinline__ f4 ldccf4(const float* p){
    f4 r;
    asm volatile("global_load_dwordx4 %0, %1, off sc0 sc1" : "=v"(r) : "v"(p));
    return r;
}
__device__ __forceinline__ void stcc16(u16* p, u32x4 v){
    asm volatile("global_store_dwordx4 %0, %1, off sc0 sc1" :: "v"(p), "v"(v) : "memory");
}
__device__ __forceinline__ void stccf(float* p, float v){
    asm volatile("global_store_dword %0, %1, off sc0 sc1" :: "v"(p), "v"(v) : "memory");
}
// drain all vmem; sched_barrier stops MFMA/VALU hoisting above it (rule 18)
__device__ __forceinline__ void waitvm0(){
    asm volatile("s_waitcnt vmcnt(0)" ::: "memory");
    __builtin_amdgcn_sched_barrier(0);
}

// ---------------- h0 -> bf16 h fragments: hff[b][hh][k][sel][lane][8] ----------------
__global__ void conv_k(const float* __restrict__ h0, u16* __restrict__ hws){
    int f = blockIdx.x * blockDim.x + threadIdx.x;     // 65536 frags
    int l   = f & 63;
    int sel = (f >> 6) & 1;
    int k   = (f >> 7) & 31;
    int hh  = (f >> 12) & 1;
    int row = hh*32 + sel*16 + (l & 15);
    int col = k*32 + (l >> 4)*8;
    bf8 p = ld8bf(h0 + (size_t)row*NV + col);
    *(bf8*)(hws + (size_t)f*8) = p;
}

// ---------------- graph -> bf16 B-fragments: gff[tile][wt][k][lane][8] ----------------
__global__ void frag_k(const float* __restrict__ g, u16* __restrict__ gff){
    int f = blockIdx.x * blockDim.x + threadIdx.x;     // 131072 frags
    int l    = f & 63;
    int k    = (f >> 6) & 31;
    int wt   = (f >> 11) & 1;
    int tile = f >> 12;
    int row = tile*32 + wt*16 + (l & 15);
    int col = k*32 + (l >> 4)*8;
    bf8 p = ld8bf(g + (size_t)row*NV + col);
    *(bf8*)(gff + (size_t)f*8) = p;
}

// ---------------- pre-transpose x/mask: xmt[b][t][v] = mask ? x : +INF ----------------
__global__ void prep_k(const float* __restrict__ x, const int* __restrict__ mask,
                       float* __restrict__ xmt){
    __shared__ float tx[64][65];
    __shared__ int   tm[64][65];
    int b  = blockIdx.x >> 4;
    int v0 = (blockIdx.x & 15) << 6;
    int tid = threadIdx.x;
    int q = tid >> 6, l = tid & 63;
    #pragma unroll 4
    for (int r = 0; r < 16; ++r){
        int vv = r*4 + q;
        size_t idx = ((size_t)b*NV + v0 + vv)*64 + l;   // x[b][0][v][t], coalesced in t
        tx[vv][l] = x[idx];
        tm[vv][l] = mask[idx];
    }
    __syncthreads();
    #pragma unroll 4
    for (int r = 0; r < 16; ++r){
        int tt = r*4 + q;
        float xv = tx[l][tt];
        xmt[((size_t)b*NSTEP + tt)*NV + v0 + l] = tm[l][tt] ? xv : __builtin_inff();
    }
}

// ---------------- preds[t=0] = W_init . h0 + b_init ; zero barrier counters ----------------
__global__ void init_k(const float* __restrict__ h0, const float* __restrict__ Wini,
                       const float* __restrict__ bini, float* __restrict__ out,
                       float* __restrict__ predsT){
    if (blockIdx.x == 0 && threadIdx.x < 128) g_bar[threadIdx.x] = 0;
    int v = blockIdx.x * blockDim.x + threadIdx.x;
    if (v < NV){
        float s = 0.f;
        for (int h = 0; h < HID; ++h) s += h0[h*NV + v] * Wini[h];
        s += bini[0];
        for (int b = 0; b < BS; ++b){
            out[PREDS_OFF + (size_t)b*65536 + (size_t)v*64] = s;
            predsT[(size_t)b*NSTEP*NV + v] = s;
        }
    }
}

// ---------------- persistent recurrence: fence-free cross-block exchange ----------------
// grid: 256 blocks = 8 batches x 32 node-tiles = 1 block/CU. 4 waves (2 wt x 2 hh).
// Cross-step shared data (hws, predsT) moves via sc0sc1 (LLC write-through / fresh reads).
// Read-only operands use normal cached loads and are NEVER invalidated (no threadfence).
__global__ __launch_bounds__(256, 1) void persist_k(
    u16* __restrict__ hws,
    const u16* __restrict__ gff, const float* __restrict__ ig,
    const float* __restrict__ Whh,
    const float* __restrict__ xmt, float* __restrict__ predsT,
    const float* __restrict__ Wih, const float* __restrict__ bih,
    const float* __restrict__ bhh,
    const float* __restrict__ Wini, const float* __restrict__ bini,
    const float* __restrict__ Wo, const float* __restrict__ bo,
    float* out, float* __restrict__ rtmp, int staged)
{
    __shared__ float xh_s[NV];                  // 4 KB
    __shared__ __align__(16) u16 hdb[32][72];   // 4.6 KB  h_diff bf16 [w][h]
    __shared__ __align__(16) float hnf[32][68]; // 8.5 KB  h_new  f32 [w][h]
    __shared__ float xg_s[32];
    __shared__ float r1[8][33], r2[8][33];

    const int tid  = threadIdx.x;
    const int b    = blockIdx.x >> 5;           // batch
    const int tile = blockIdx.x & 31;           // node tile
    const int w0   = tile << 5;
    const int lane = tid & 63;
    const int wv   = tid >> 6;
    const int wt   = wv & 1;                    // w 16-tile
    const int hh   = wv >> 1;                   // h 32-half
    const int m16  = lane & 15;
    const int q    = lane >> 4;

    // ---- W_hh fragments: t-invariant, loaded ONCE (normal cached loads) ----
    bf8 wf[3][2][2];
    #pragma unroll
    for (int gi = 0; gi < 3; ++gi)
        #pragma unroll
        for (int ht = 0; ht < 2; ++ht)
            #pragma unroll
            for (int ks = 0; ks < 2; ++ks)
                wf[gi][ht][ks] = ld8bf(Whh
                    + (size_t)(gi*64 + hh*32 + ht*16 + m16)*64 + ks*32 + q*8);

    const u16* gB = gff + ((size_t)(tile*2 + wt)*32)*512 + lane*8;
    const int v4 = tid * 4;
    int* const cb = g_bar + (b << 4);           // this batch's 64B-padded counter

    #pragma unroll 1
    for (int t = 0; t < NSTEP; ++t){
        const u16* hin  = hws + (size_t)(t & 1) * HSTRIDE;
        u16*       hout = hws + (size_t)((t+1) & 1) * HSTRIDE;

        // ---- phase 0a: xmt normal (read-only), predsT coherent ----
        float4 xm = *(const float4*)(xmt + ((size_t)b*NSTEP + t)*NV + v4);
        f4 pv = ldccf4(predsT + ((size_t)b*NSTEP + t)*NV + v4);

        // ---- phase 2: h_diff = h . graph^T ; h via batched coherent loads, gff cached ----
        const u16* hA = hin + (size_t)b*65536 + (size_t)hh*32768 + lane*8;
        f4 accA0 = {0.f,0.f,0.f,0.f}, accA1 = {0.f,0.f,0.f,0.f};
        #pragma unroll 1
        for (int g = 0; g < 8; ++g){
            const u16* gk = gB + (size_t)g*2048;
            bf8 g0 = *(const bf8*)(gk);            // normal cached loads (issued early)
            bf8 g1 = *(const bf8*)(gk + 512);
            bf8 g2 = *(const bf8*)(gk + 1024);
            bf8 g3 = *(const bf8*)(gk + 1536);
            const u16* hk = hA + (size_t)g*4096;
            bf8 a00 = ldcc(hk);                    // coherent loads, batched
            bf8 a10 = ldcc(hk + 512);
            bf8 a01 = ldcc(hk + 1024);
            bf8 a11 = ldcc(hk + 1536);
            bf8 a02 = ldcc(hk + 2048);
            bf8 a12 = ldcc(hk + 2560);
            bf8 a03 = ldcc(hk + 3072);
            bf8 a13 = ldcc(hk + 3584);
            waitvm0();                              // one drain per 8 loads
            accA0 = __builtin_amdgcn_mfma_f32_16x16x32_bf16(a00, g0, accA0, 0, 0, 0);
            accA1 = __builtin_amdgcn_mfma_f32_16x16x32_bf16(a10, g0, accA1, 0, 0, 0);
            accA0 = __builtin_amdgcn_mfma_f32_16x16x32_bf16(a01, g1, accA0, 0, 0, 0);
            accA1 = __builtin_amdgcn_mfma_f32_16x16x32_bf16(a11, g1, accA1, 0, 0, 0);
            accA0 = __builtin_amdgcn_mfma_f32_16x16x32_bf16(a02, g2, accA0, 0, 0, 0);
            accA1 = __builtin_amdgcn_mfma_f32_16x16x32_bf16(a12, g2, accA1, 0, 0, 0);
            accA0 = __builtin_amdgcn_mfma_f32_16x16x32_bf16(a03, g3, accA0, 0, 0, 0);
            accA1 = __builtin_amdgcn_mfma_f32_16x16x32_bf16(a13, g3, accA1, 0, 0, 0);
        }
        // acc: col = m16 -> w = wt*16+m16 ; row = q*4+r -> h = hh*32 + sel*16 + q*4+r

        // ---- phase 0b: x_hat select + h_diff publish (pv drained by last waitvm0) ----
        waitvm0();
        {
            float4 xh;
            xh.x = (__float_as_uint(xm.x) == 0x7f800000u) ? pv.x : xm.x;
            xh.y = (__float_as_uint(xm.y) == 0x7f800000u) ? pv.y : xm.y;
            xh.z = (__float_as_uint(xm.z) == 0x7f800000u) ? pv.z : xm.z;
            xh.w = (__float_as_uint(xm.w) == 0x7f800000u) ? pv.w : xm.w;
            *(float4*)&xh_s[v4] = xh;
        }
        #pragma unroll
        for (int ht = 0; ht < 2; ++ht){
            f4 a = ht ? accA1 : accA0;
            ushort4 pk;
            pk.x = f2bf(a[0]); pk.y = f2bf(a[1]); pk.z = f2bf(a[2]); pk.w = f2bf(a[3]);
            *(ushort4*)&hdb[wt*16 + m16][hh*32 + ht*16 + q*4] = pk;
        }
        __syncthreads();   // B1: xh_s + hdb ready

        // ---- phase 1: x_g[w] = sum_v ig[w][v]*x_hat[v] (f32 cached, shfl reduce) ----
        {
            int w = tid >> 3, p = tid & 7;
            const float* igr = ig + (size_t)(w0 + w)*NV + p*8;
            float acc = 0.f;
            #pragma unroll
            for (int k = 0; k < 16; ++k){
                float4 ga = *(const float4*)(igr + k*64);
                float4 gc = *(const float4*)(igr + k*64 + 4);
                const float* xv = &xh_s[p*8 + k*64];
                acc += ga.x*xv[0] + ga.y*xv[1] + ga.z*xv[2] + ga.w*xv[3]
                     + gc.x*xv[4] + gc.y*xv[5] + gc.z*xv[6] + gc.w*xv[7];
            }
            acc += __shfl_xor(acc, 1);
            acc += __shfl_xor(acc, 2);
            acc += __shfl_xor(acc, 4);
            if (p == 0) xg_s[w] = acc;
        }

        // ---- phase 3: gh = W_hh . h_diff (K=64): A = wf regs, B = hdb ----
        f4 accG[3][2];
        #pragma unroll
        for (int i = 0; i < 3; ++i){ accG[i][0] = (f4){0,0,0,0}; accG[i][1] = (f4){0,0,0,0}; }
        #pragma unroll
        for (int ks = 0; ks < 2; ++ks){
            bf8 bfr = *(const bf8*)&hdb[wt*16 + m16][ks*32 + q*8];
            #pragma unroll
            for (int gi = 0; gi < 3; ++gi){
                #pragma unroll
                for (int ht = 0; ht < 2; ++ht){
                    accG[gi][ht] = __builtin_amdgcn_mfma_f32_16x16x32_bf16(
                        wf[gi][ht][ks], bfr, accG[gi][ht], 0, 0, 0);
                }
            }
        }
        __syncthreads();   // B2: xg_s ready

        // ---- phase 4: GRU elementwise (h_diff straight from accA regs) ----
        {
            int wme = wt*16 + m16;
            float xg = xg_s[wme];
            #pragma unroll
            for (int ht = 0; ht < 2; ++ht){
                f4 hd4 = ht ? accA1 : accA0;
                f4 hn4;
                int hb4 = hh*32 + ht*16 + q*4;
                #pragma unroll
                for (int r = 0; r < 4; ++r){
                    int h = hb4 + r;
                    float ir  = xg * Wih[h]       + bih[h];
                    float iz  = xg * Wih[64 + h]  + bih[64 + h];
                    float inn = xg * Wih[128 + h] + bih[128 + h];
                    float hr  = accG[0][ht][r] + bhh[h];
                    float hz  = accG[1][ht][r] + bhh[64 + h];
                    float hnn = accG[2][ht][r] + bhh[128 + h];
                    float rg = 1.f / (1.f + __expf(-(ir + hr)));
                    float zg = 1.f / (1.f + __expf(-(iz + hz)));
                    float ng = tanhf(inn + rg * hnn);
                    hn4[r] = (1.f - zg) * ng + zg * hd4[r];
                }
                *(f4*)&hnf[wme][hb4] = hn4;
            }
        }
        __syncthreads();   // B3: hnf ready

        // ---- phase 5: outputs ----
        {   // head partial dots over h (8 groups of 8)
            int w2 = tid & 31, hg = tid >> 5;
            float s1 = 0.f, s2 = 0.f;
            #pragma unroll
            for (int j = 0; j < 8; ++j){
                float hv = hnf[w2][hg*8 + j];
                s1 += Wini[hg*8 + j] * hv;
                s2 += Wo[hg*8 + j]   * hv;
            }
            r1[hg][w2] = s1; r2[hg][w2] = s2;
        }
        {   // h_out coherent (write-through); rtmp/out normal
            int h = tid >> 2, wq = tid & 3;
            float vals[8];
            #pragma unroll
            for (int j = 0; j < 8; ++j) vals[j] = hnf[wq*8 + j][h];
            union { u16 pk[8]; u32x4 v; } u;
            #pragma unroll
            for (int j = 0; j < 8; ++j) u.pk[j] = f2bf(vals[j]);
            size_t ho = (size_t)b*65536
                      + ((size_t)((h >> 5)*32 + tile)*2 + ((h >> 4) & 1))*512
                      + wq*128 + (h & 15)*8;
            stcc16(hout + ho, u.v);
            if (staged){
                float* rp = rtmp + (((size_t)t*BS + b)*HID + h)*NV + w0 + wq*8;
                float4 a = {vals[0], vals[1], vals[2], vals[3]};
                float4 c = {vals[4], vals[5], vals[6], vals[7]};
                *(float4*)rp       = a;
                *(float4*)(rp + 4) = c;
            } else {
                size_t rb = REPRS_OFF + (((size_t)b*HID + h)*NV + w0 + wq*8)*64 + t;
                #pragma unroll
                for (int j = 0; j < 8; ++j) out[rb + (size_t)j*64] = vals[j];
            }
        }
        __syncthreads();   // B4: r1/r2 ready
        if (tid < 32){
            int w = tid, wg = w0 + w;
            float s1 = 0.f, s2 = 0.f;
            #pragma unroll
            for (int hg = 0; hg < 8; ++hg){ s1 += r1[hg][w]; s2 += r2[hg][w]; }
            s1 += bini[0]; s2 += bo[0];
            size_t base = (size_t)b*65536 + (size_t)wg*64;
            out[IMPS_OFF + base + t] = s2;                 // imps[t]
            if (t < NSTEP - 1){
                out[PREDS_OFF + base + t + 1] = s1;        // preds[t+1]
                stccf(predsT + ((size_t)b*NSTEP + t + 1)*NV + wg, s1);  // coherent
            }
        }

        // ---- per-batch barrier: NO threadfence; waitvm drains write-through stores ----
        if (t < NSTEP - 1){
            waitvm0();                       // all sc0sc1 stores at LLC
            __syncthreads();                 // B5: whole block drained
            if (tid == 0){
                __hip_atomic_fetch_add(cb, 1, __ATOMIC_RELAXED, __HIP_MEMORY_SCOPE_AGENT);
                int target = 32 * (t + 1);
                while (__hip_atomic_load(cb, __ATOMIC_RELAXED, __HIP_MEMORY_SCOPE_AGENT) < target)
                    __builtin_amdgcn_s_sleep(2);
            }
            __syncthreads();                 // B6: proceed; reads are coherent anyway
        }
    }
}

// ---------------- reprs staging [t][b][h][v] -> out [b][h][v][t] ----------------
__global__ void transpose_k(const float* __restrict__ rtmp, float* __restrict__ out){
    __shared__ float tile[64][65];
    int bh = blockIdx.x >> 4;          // 0..511 = b*64 + h
    int b  = bh >> 6, h = bh & 63;
    int v0 = (blockIdx.x & 15) << 6;
    int tid = threadIdx.x;
    int q = tid >> 6, l = tid & 63;
    #pragma unroll 4
    for (int r = 0; r < 16; ++r){
        int tt = r*4 + q;
        tile[tt][l] = rtmp[(((size_t)tt*BS + b)*HID + h)*NV + v0 + l];
    }
    __syncthreads();
    #pragma unroll 4
    for (int r = 0; r < 16; ++r){
        int vv = r*4 + q;
        out[REPRS_OFF + (((size_t)b*HID + h)*NV + v0 + vv)*64 + l] = tile[l][vv];
    }
}

extern "C" void kernel_launch(void* const* d_in, const int* in_sizes, int n_in,
                              void* d_out, int out_size, void* d_ws, size_t ws_size,
                              hipStream_t stream) {
    const float* x     = (const float*)d_in[0];
    const int*   mask  = (const int*)  d_in[1];
    const float* graph = (const float*)d_in[2];
    const float* ind   = (const float*)d_in[3];
    const float* h0    = (const float*)d_in[4];
    const float* Wini  = (const float*)d_in[5];
    const float* bini  = (const float*)d_in[6];
    const float* Wo    = (const float*)d_in[7];
    const float* bo    = (const float*)d_in[8];
    const float* Wih   = (const float*)d_in[9];
    const float* Whh   = (const float*)d_in[10];
    const float* bih   = (const float*)d_in[11];
    const float* bhh   = (const float*)d_in[12];
    float* out = (float*)d_out;

    char* ws = (char*)d_ws;
    u16*   hws    = (u16*)(ws);                         // 2 x 1 MB bf16 h frags ping-pong
    u16*   gff    = (u16*)(ws + ((size_t)2<<20));       // 2 MB graph B-frags
    float* xmt    = (float*)(ws + ((size_t)4<<20));     // 2 MB x/mask merged transposed
    float* predsT = (float*)(ws + ((size_t)6<<20));     // 2 MB preds in [b][t][v]
    float* rtmp   = (float*)(ws + ((size_t)8<<20));     // 128 MB reprs staging
    size_t need_staged = ((size_t)8<<20) + (size_t)NSTEP*BS*HID*NV*4;
    int staged = (ws_size >= need_staged) ? 1 : 0;

    conv_k<<<dim3(256), dim3(256), 0, stream>>>(h0, hws);
    frag_k<<<dim3(512), dim3(256), 0, stream>>>(graph, gff);
    prep_k<<<dim3(128), dim3(256), 0, stream>>>(x, mask, xmt);
    init_k<<<dim3(4), dim3(256), 0, stream>>>(h0, Wini, bini, out, predsT);

    persist_k<<<dim3(256), dim3(256), 0, stream>>>(
        hws, gff, ind, Whh, xmt, predsT,
        Wih, bih, bhh, Wini, bini, Wo, bo, out, rtmp, staged);

    if (staged) transpose_k<<<dim3(8192), dim3(256), 0, stream>>>(rtmp, out);
}